// Round 20
// baseline (102.728 us; speedup 1.0000x reference)
//
#include <hip/hip_runtime.h>
#include <hip/hip_bf16.h>

// Problem constants
#define BHALF 4096      // B = 8192/2
#define DDIM 128        // feature dim per matrix
#define KCAT 384        // 3*DDIM, packed row width
#define TEMP_INV 10.0f  // 1/TEMP
#define EXP2K 14.426950408889634f  // 10 * log2(e): exp(v*10) = exp2(v*EXP2K)

// parts layout (floats): row-type arrays 64 slots, col-type arrays 128 slots
//   [rs0 64 | rs1 64 | rs2 64 | rs3 64 | cs0 128 | cs1 128 | cs2 128] x 4096
#define OFF_RS0 0
#define OFF_RS1 (64 * 4096)
#define OFF_RS2 (128 * 4096)
#define OFF_RS3 (192 * 4096)
#define OFF_CS0 (256 * 4096)
#define OFF_CS1 (384 * 4096)
#define OFF_CS2 (512 * 4096)
#define PARTS_TOTAL (640 * 4096)

typedef __attribute__((ext_vector_type(8))) short short8;   // 8 bf16
typedef __attribute__((ext_vector_type(4))) float f32x4;    // 16x16 MFMA acc

// Async global->LDS, 16B per lane. LDS dest is wave-uniform base (HW adds
// lane*16). Global source is per-lane.
__device__ __forceinline__ void gload16(const ushort* g, ushort* l) {
  __builtin_amdgcn_global_load_lds(
      (const __attribute__((address_space(1))) unsigned int*)g,
      (__attribute__((address_space(3))) unsigned int*)l, 16, 0, 0);
}

// ---------------------------------------------------------------------------
// Fused normalize + diag: one wave per (matrix, row-pair i). [verbatim]
__global__ __launch_bounds__(256) void norm_diag_kernel(
    const float* __restrict__ x, const float* __restrict__ y,
    const float* __restrict__ z, ushort* __restrict__ nrm1,
    ushort* __restrict__ nrm2, float* __restrict__ dxyz) {
  int wave = threadIdx.x >> 6;
  int lane = threadIdx.x & 63;
  int gi = blockIdx.x * 4 + wave;  // 0 .. 3*4096-1
  int mat = gi >> 12;
  int i = gi & 4095;
  const float* src = (mat == 0 ? x : (mat == 1 ? y : z));
  float2 a = *(const float2*)(src + (size_t)i * DDIM + lane * 2);
  float2 b = *(const float2*)(src + (size_t)(i + BHALF) * DDIM + lane * 2);
  float s1 = a.x * a.x + a.y * a.y;
  float s2 = b.x * b.x + b.y * b.y;
  float d = a.x * b.x + a.y * b.y;
#pragma unroll
  for (int m = 1; m < 64; m <<= 1) {
    s1 += __shfl_xor(s1, m, 64);
    s2 += __shfl_xor(s2, m, 64);
    d += __shfl_xor(d, m, 64);
  }
  float r1 = 1.0f / fmaxf(sqrtf(s1), 1e-12f);
  float r2 = 1.0f / fmaxf(sqrtf(s2), 1e-12f);
  ushort* d1 = nrm1 + (size_t)i * KCAT + mat * DDIM + lane * 2;
  ushort* d2 = nrm2 + (size_t)i * KCAT + mat * DDIM + lane * 2;
  __hip_bfloat162 o1, o2;
  o1.x = __float2bfloat16(a.x * r1);
  o1.y = __float2bfloat16(a.y * r1);
  o2.x = __float2bfloat16(b.x * r2);
  o2.y = __float2bfloat16(b.y * r2);
  *(__hip_bfloat162*)d1 = o1;
  *(__hip_bfloat162*)d2 = o2;
  if (lane == 0) dxyz[mat * BHALF + i] = d * r1 * r2;
}

// ---------------------------------------------------------------------------
// Flush helpers for the 8-wave 32x64 wave tile (acc[2][4]). Plain stores to
// unique per-(block,wave) slots (no atomics).
// 16x16 C/D layout (verified): col = lane&15, row = (lane>>4)*4 + r.

// g3^T (operand-swapped mfma(bf, af)): D rows = b-cols, D cols = a-rows.
// Sum over all D rows (n, r, lane>>4 groups) -> one value per a-row.
__device__ __forceinline__ void flush_cheap8(f32x4 (&acc)[2][4],
                                             float* __restrict__ dst,
                                             int base, int lane) {
#pragma unroll
  for (int m = 0; m < 2; ++m) {
    float s = 0.0f;
#pragma unroll
    for (int n = 0; n < 4; ++n)
#pragma unroll
      for (int r = 0; r < 4; ++r) s += exp2f(acc[m][n][r] * EXP2K);
    s += __shfl_xor(s, 16, 64);
    s += __shfl_xor(s, 32, 64);
    if (lane < 16) dst[base + m * 16 + lane] = s;
  }
}

// Full flush: D[i][j]; rs[i] = sum over this wave's 64 cols,
// cs[j] = sum over this wave's 32 rows.
__device__ __forceinline__ void flush_full8(f32x4 (&acc)[2][4],
                                            float* __restrict__ rs,
                                            float* __restrict__ cs, int rbase,
                                            int cbase, int lane) {
#pragma unroll
  for (int m = 0; m < 2; ++m)
#pragma unroll
    for (int n = 0; n < 4; ++n)
#pragma unroll
      for (int r = 0; r < 4; ++r)
        acc[m][n][r] = exp2f(acc[m][n][r] * EXP2K);

  // row sums: reduce over cols (n + xor over lane&15)
#pragma unroll
  for (int m = 0; m < 2; ++m) {
    float rsum[4];
#pragma unroll
    for (int r = 0; r < 4; ++r)
      rsum[r] = acc[m][0][r] + acc[m][1][r] + acc[m][2][r] + acc[m][3][r];
#pragma unroll
    for (int r = 0; r < 4; ++r) {
      rsum[r] += __shfl_xor(rsum[r], 1, 64);
      rsum[r] += __shfl_xor(rsum[r], 2, 64);
      rsum[r] += __shfl_xor(rsum[r], 4, 64);
      rsum[r] += __shfl_xor(rsum[r], 8, 64);
    }
    if ((lane & 15) == 0) {
      int rb = rbase + m * 16 + (lane >> 4) * 4;
#pragma unroll
      for (int r = 0; r < 4; ++r) rs[rb + r] = rsum[r];
    }
  }

  // col sums: reduce over rows (m, r, xor16, xor32)
#pragma unroll
  for (int n = 0; n < 4; ++n) {
    float csum = 0.0f;
#pragma unroll
    for (int m = 0; m < 2; ++m)
#pragma unroll
      for (int r = 0; r < 4; ++r) csum += acc[m][n][r];
    csum += __shfl_xor(csum, 16, 64);
    csum += __shfl_xor(csum, 32, 64);
    if (lane < 16) cs[cbase + n * 16 + lane] = csum;
  }
}

// ---------------------------------------------------------------------------
// Gram kernel v13 "8-wave": R13's 4x-passed slab core (same 128x128 tile,
// same As/Bs[4][128][32] 64KB LDS, same 4-kslice slab loop, same barriers,
// same swizzles, same XCD tile swizzle) with EIGHT waves per block
// (wave tile 32x64, acc[2][4] = 32 VGPR). 2 blocks/CU x 8 waves =
// 16 waves/CU = 4/SIMD — the isolated intra-block-TLP experiment.
// g3 (K=384): 3 slabs, operand-swapped; g0/g1/g2 (K=128): 1 slab.
__global__ __launch_bounds__(512) void gram_slab_kernel(
    const ushort* __restrict__ nrm1, const ushort* __restrict__ nrm2,
    float* __restrict__ parts) {
  __shared__ ushort As[4][128][32];  // 32 KB, kslice-major (64B rows)
  __shared__ ushort Bs[4][128][32];  // 32 KB

  int tid = threadIdx.x;
  int lane = tid & 63;
  int wave = tid >> 6;  // 0..7
  int wr = wave >> 1;   // 0..3: rows wr*32
  int wc = wave & 1;    // 0..1: cols wc*64
  int g = (blockIdx.z == 0) ? 3 : (int)blockIdx.z - 1;  // heavy g3 first
  // XCD-aware swizzle (R18-verified: FETCH 21->13.9 MB).
  int fid = (int)blockIdx.x + 32 * (int)blockIdx.y;  // 0..1023 in phase
  int swz = (fid & 7) * 128 + (fid >> 3);
  int bi = swz & 31;
  int bj = swz >> 5;
  int rowbase = bi * 128;
  int colbase = bj * 128;

  const ushort* Ab;
  const ushort* Bb;
  int nslab;
  float* rs;  // row-type slot base (slot = bj*2 + wc, 64 slots)
  float* cs;  // col-type slot base (slot = bi*4 + wr, 128 slots)
  int rslot = (bj * 2 + wc) * 4096;
  int cslot = (bi * 4 + wr) * 4096;
  if (g == 3) {
    Ab = nrm1;       Bb = nrm2;       nslab = 3;
    rs = parts + OFF_RS3 + rslot; cs = nullptr;
  } else if (g == 0) {
    Ab = nrm1;       Bb = nrm1 + 128; nslab = 1;
    rs = parts + OFF_RS0 + rslot; cs = parts + OFF_CS0 + cslot;
  } else if (g == 1) {
    Ab = nrm1;       Bb = nrm1 + 256; nslab = 1;
    rs = parts + OFF_RS1 + rslot; cs = parts + OFF_CS1 + cslot;
  } else {
    Ab = nrm1 + 128; Bb = nrm1 + 256; nslab = 1;
    rs = parts + OFF_RS2 + rslot; cs = parts + OFF_CS2 + cslot;
  }

  // Staging: each wave stages rows [wave*16, +16) of A and B per kslice
  // (8 waves x 16 = 128 rows). Lane l -> row +(l>>2), chunk (l&3); source
  // chunk pre-swizzled by ((l>>3)&3) = ((row mod 16)>>1)&3 (R2-verified).
  int srow = lane >> 2;
  int schunk = ((lane & 3) ^ ((lane >> 3) & 3)) << 3;
  const ushort* gA =
      Ab + (size_t)(rowbase + wave * 16 + srow) * KCAT + schunk;
  const ushort* gB =
      Bb + (size_t)(colbase + wave * 16 + srow) * KCAT + schunk;

  // Fragment reads: row = grp*16 + rsel, logical chunk = lane>>4,
  // physical slot = chunk ^ ((rsel>>1)&3).
  int rsel = lane & 15;
  int slot8 = (((lane >> 4) ^ ((rsel >> 1) & 3)) << 3);

  f32x4 acc[2][4] = {};

  for (int slab = 0; slab < nslab; ++slab) {
    if (slab) {
      __builtin_amdgcn_s_barrier();       // prev slab reads done everywhere
      __builtin_amdgcn_sched_barrier(0);  // keep stage below the barrier
    }
    int k0 = slab * 128;
#pragma unroll
    for (int s = 0; s < 4; ++s) {
      gload16(gA + k0 + s * 32, &As[s][wave * 16][0]);
      gload16(gB + k0 + s * 32, &Bs[s][wave * 16][0]);
    }
    asm volatile("s_waitcnt vmcnt(0)" ::: "memory");
    __builtin_amdgcn_s_barrier();
    __builtin_amdgcn_sched_barrier(0);  // no LDS-read hoisting above barrier

    if (g == 3) {
#pragma unroll
      for (int kk = 0; kk < 4; ++kk) {
        short8 af[2], bf[4];
#pragma unroll
        for (int m = 0; m < 2; ++m)
          af[m] = *(const short8*)&As[kk][wr * 32 + m * 16 + rsel][slot8];
#pragma unroll
        for (int n = 0; n < 4; ++n)
          bf[n] = *(const short8*)&Bs[kk][wc * 64 + n * 16 + rsel][slot8];
#pragma unroll
        for (int m = 0; m < 2; ++m)
#pragma unroll
          for (int n = 0; n < 4; ++n)
            acc[m][n] = __builtin_amdgcn_mfma_f32_16x16x32_bf16(
                bf[n], af[m], acc[m][n], 0, 0, 0);
      }
    } else {
#pragma unroll
      for (int kk = 0; kk < 4; ++kk) {
        short8 af[2], bf[4];
#pragma unroll
        for (int m = 0; m < 2; ++m)
          af[m] = *(const short8*)&As[kk][wr * 32 + m * 16 + rsel][slot8];
#pragma unroll
        for (int n = 0; n < 4; ++n)
          bf[n] = *(const short8*)&Bs[kk][wc * 64 + n * 16 + rsel][slot8];
#pragma unroll
        for (int m = 0; m < 2; ++m)
#pragma unroll
          for (int n = 0; n < 4; ++n)
            acc[m][n] = __builtin_amdgcn_mfma_f32_16x16x32_bf16(
                af[m], bf[n], acc[m][n], 0, 0, 0);
      }
    }
  }

  if (g == 3)
    flush_cheap8(acc, rs, rowbase + wr * 32, lane);
  else
    flush_full8(acc, rs, cs, rowbase + wr * 32, colbase + wc * 64, lane);
}

// ---------------------------------------------------------------------------
// Stage 1: fold partial slots (row arrays 64 slots, col arrays 128).
// Grid 112 x 256, one thread per (array, i). Coalesced.
__global__ __launch_bounds__(256) void reduce_parts_kernel(
    const float* __restrict__ parts, float* __restrict__ sums7) {
  int f = blockIdx.x * 256 + threadIdx.x;  // 0 .. 7*4096-1
  int a = f >> 12;                         // 0..6
  int i = f & 4095;
  int off = (a < 4) ? a * 64 : 256 + (a - 4) * 128;  // slot-array base (x4096)
  int cnt = (a < 4) ? 64 : 128;
  const float* p = parts + (size_t)off * 4096 + i;
  float s = 0.0f;
  for (int slot = 0; slot < cnt; ++slot) s += p[(size_t)slot * 4096];
  sums7[f] = s;  // order: rs0, rs1, rs2, rs3, cs0, cs1, cs2
}

// ---------------------------------------------------------------------------
// Stage 2: final loss from folded sums (163 KB). Single block, plain store.
__global__ __launch_bounds__(256) void loss_kernel(
    const float* __restrict__ s7, const float* __restrict__ dxyz,
    float* __restrict__ out) {
  int tid = threadIdx.x;
  float acc = 0.0f;
  for (int i = tid; i < BHALF; i += 256) {
    float rs0 = s7[i];
    float rs1 = s7[4096 + i];
    float rs2 = s7[2 * 4096 + i];
    float rs3 = s7[3 * 4096 + i];
    float cs0 = s7[4 * 4096 + i];
    float cs1 = s7[5 * 4096 + i];
    float cs2 = s7[6 * 4096 + i];
    float dxv = dxyz[i];
    float dyv = dxyz[4096 + i];
    float dzv = dxyz[2 * 4096 + i];
    float lx = logf(rs0 + rs1) - TEMP_INV * dxv;
    float ly = logf(cs0 + rs2) - TEMP_INV * dyv;
    float lz = logf(cs1 + cs2) - TEMP_INV * dzv;
    float lv = logf(rs3) - TEMP_INV * (dxv + dyv + dzv);
    acc += lx + ly + lz + lv;
  }
  __shared__ float red[4];
#pragma unroll
  for (int m = 1; m < 64; m <<= 1) acc += __shfl_xor(acc, m, 64);
  if ((tid & 63) == 0) red[tid >> 6] = acc;
  __syncthreads();
  if (tid == 0)
    out[0] = (red[0] + red[1] + red[2] + red[3]) * (1.0f / 4096.0f);
}

// ---------------------------------------------------------------------------
extern "C" void kernel_launch(void* const* d_in, const int* in_sizes, int n_in,
                              void* d_out, int out_size, void* d_ws,
                              size_t ws_size, hipStream_t stream) {
  const float* x = (const float*)d_in[0];
  const float* y = (const float*)d_in[1];
  const float* z = (const float*)d_in[2];
  char* ws = (char*)d_ws;
  ushort* nrm1 = (ushort*)ws;                       // 4096*384 bf16
  ushort* nrm2 = nrm1 + (size_t)BHALF * KCAT;       // 4096*384 bf16
  float* parts = (float*)(ws + 2 * (size_t)BHALF * KCAT * sizeof(ushort));
  float* dxyz = parts + PARTS_TOTAL;                // 3*4096 fp32
  float* sums7 = dxyz + 3 * 4096;                   // 7*4096 fp32

  norm_diag_kernel<<<3 * BHALF / 4, 256, 0, stream>>>(x, y, z, nrm1, nrm2,
                                                      dxyz);
  gram_slab_kernel<<<dim3(32, 32, 4), 512, 0, stream>>>(nrm1, nrm2, parts);
  reduce_parts_kernel<<<112, 256, 0, stream>>>(parts, sums7);
  loss_kernel<<<1, 256, 0, stream>>>(sums7, dxyz, (float*)d_out);
}

// Round 21
// 72.002 us; speedup vs baseline: 1.4267x; 1.4267x over previous
//
#include <hip/hip_runtime.h>
#include <hip/hip_bf16.h>

// Problem constants
#define BHALF 4096      // B = 8192/2
#define DDIM 128        // feature dim per matrix
#define KCAT 384        // 3*DDIM, packed row width
#define TEMP_INV 10.0f  // 1/TEMP
#define EXP2K 14.426950408889634f  // 10 * log2(e): exp(v*10) = exp2(v*EXP2K)

// parts layout (floats): row-type arrays 64 slots, col-type arrays 128 slots
//   [rs0 64 | rs1 64 | rs2 64 | rs3 64 | cs0 128 | cs1 128 | cs2 128] x 4096
#define OFF_RS0 0
#define OFF_RS1 (64 * 4096)
#define OFF_RS2 (128 * 4096)
#define OFF_RS3 (192 * 4096)
#define OFF_CS0 (256 * 4096)
#define OFF_CS1 (384 * 4096)
#define OFF_CS2 (512 * 4096)
#define PARTS_TOTAL (640 * 4096)

typedef __attribute__((ext_vector_type(8))) short short8;   // 8 bf16
typedef __attribute__((ext_vector_type(4))) float f32x4;    // 16x16 MFMA acc

// Async global->LDS, 16B per lane. LDS dest is wave-uniform base (HW adds
// lane*16). Global source is per-lane.
__device__ __forceinline__ void gload16(const ushort* g, ushort* l) {
  __builtin_amdgcn_global_load_lds(
      (const __attribute__((address_space(1))) unsigned int*)g,
      (__attribute__((address_space(3))) unsigned int*)l, 16, 0, 0);
}

// ---------------------------------------------------------------------------
// Fused normalize + diag: one wave per (matrix, row-pair i). [verbatim]
__global__ __launch_bounds__(256) void norm_diag_kernel(
    const float* __restrict__ x, const float* __restrict__ y,
    const float* __restrict__ z, ushort* __restrict__ nrm1,
    ushort* __restrict__ nrm2, float* __restrict__ dxyz) {
  int wave = threadIdx.x >> 6;
  int lane = threadIdx.x & 63;
  int gi = blockIdx.x * 4 + wave;  // 0 .. 3*4096-1
  int mat = gi >> 12;
  int i = gi & 4095;
  const float* src = (mat == 0 ? x : (mat == 1 ? y : z));
  float2 a = *(const float2*)(src + (size_t)i * DDIM + lane * 2);
  float2 b = *(const float2*)(src + (size_t)(i + BHALF) * DDIM + lane * 2);
  float s1 = a.x * a.x + a.y * a.y;
  float s2 = b.x * b.x + b.y * b.y;
  float d = a.x * b.x + a.y * b.y;
#pragma unroll
  for (int m = 1; m < 64; m <<= 1) {
    s1 += __shfl_xor(s1, m, 64);
    s2 += __shfl_xor(s2, m, 64);
    d += __shfl_xor(d, m, 64);
  }
  float r1 = 1.0f / fmaxf(sqrtf(s1), 1e-12f);
  float r2 = 1.0f / fmaxf(sqrtf(s2), 1e-12f);
  ushort* d1 = nrm1 + (size_t)i * KCAT + mat * DDIM + lane * 2;
  ushort* d2 = nrm2 + (size_t)i * KCAT + mat * DDIM + lane * 2;
  __hip_bfloat162 o1, o2;
  o1.x = __float2bfloat16(a.x * r1);
  o1.y = __float2bfloat16(a.y * r1);
  o2.x = __float2bfloat16(b.x * r2);
  o2.y = __float2bfloat16(b.y * r2);
  *(__hip_bfloat162*)d1 = o1;
  *(__hip_bfloat162*)d2 = o2;
  if (lane == 0) dxyz[mat * BHALF + i] = d * r1 * r2;
}

// ---------------------------------------------------------------------------
// Flush helpers for the 8-wave 32x64 wave tile (acc[2][4]). Plain stores to
// unique per-(block,wave) slots (no atomics). [R20 verbatim]
// 16x16 C/D layout (verified): col = lane&15, row = (lane>>4)*4 + r.

__device__ __forceinline__ void flush_cheap8(f32x4 (&acc)[2][4],
                                             float* __restrict__ dst,
                                             int base, int lane) {
#pragma unroll
  for (int m = 0; m < 2; ++m) {
    float s = 0.0f;
#pragma unroll
    for (int n = 0; n < 4; ++n)
#pragma unroll
      for (int r = 0; r < 4; ++r) s += exp2f(acc[m][n][r] * EXP2K);
    s += __shfl_xor(s, 16, 64);
    s += __shfl_xor(s, 32, 64);
    if (lane < 16) dst[base + m * 16 + lane] = s;
  }
}

__device__ __forceinline__ void flush_full8(f32x4 (&acc)[2][4],
                                            float* __restrict__ rs,
                                            float* __restrict__ cs, int rbase,
                                            int cbase, int lane) {
#pragma unroll
  for (int m = 0; m < 2; ++m)
#pragma unroll
    for (int n = 0; n < 4; ++n)
#pragma unroll
      for (int r = 0; r < 4; ++r)
        acc[m][n][r] = exp2f(acc[m][n][r] * EXP2K);

  // row sums: reduce over cols (n + xor over lane&15)
#pragma unroll
  for (int m = 0; m < 2; ++m) {
    float rsum[4];
#pragma unroll
    for (int r = 0; r < 4; ++r)
      rsum[r] = acc[m][0][r] + acc[m][1][r] + acc[m][2][r] + acc[m][3][r];
#pragma unroll
    for (int r = 0; r < 4; ++r) {
      rsum[r] += __shfl_xor(rsum[r], 1, 64);
      rsum[r] += __shfl_xor(rsum[r], 2, 64);
      rsum[r] += __shfl_xor(rsum[r], 4, 64);
      rsum[r] += __shfl_xor(rsum[r], 8, 64);
    }
    if ((lane & 15) == 0) {
      int rb = rbase + m * 16 + (lane >> 4) * 4;
#pragma unroll
      for (int r = 0; r < 4; ++r) rs[rb + r] = rsum[r];
    }
  }

  // col sums: reduce over rows (m, r, xor16, xor32)
#pragma unroll
  for (int n = 0; n < 4; ++n) {
    float csum = 0.0f;
#pragma unroll
    for (int m = 0; m < 2; ++m)
#pragma unroll
      for (int r = 0; r < 4; ++r) csum += acc[m][n][r];
    csum += __shfl_xor(csum, 16, 64);
    csum += __shfl_xor(csum, 32, 64);
    if (lane < 16) cs[cbase + n * 16 + lane] = csum;
  }
}

// ---------------------------------------------------------------------------
// Gram kernel v13 "8-wave" [R20 VERBATIM — passed; gram 53.4 us, occupancy
// 35%, VGPR 52, 0 conflicts]: R13's slab core (128x128 tile, 64KB LDS,
// 4-kslice slab, same barriers/swizzles/XCD-swizzle) with EIGHT waves per
// block (wave tile 32x64, acc[2][4]); 2 blocks/CU x 8 waves = 4 waves/SIMD.
// g3 (K=384): 3 slabs, operand-swapped; g0/g1/g2 (K=128): 1 slab.
__global__ __launch_bounds__(512) void gram_slab_kernel(
    const ushort* __restrict__ nrm1, const ushort* __restrict__ nrm2,
    float* __restrict__ parts) {
  __shared__ ushort As[4][128][32];  // 32 KB, kslice-major (64B rows)
  __shared__ ushort Bs[4][128][32];  // 32 KB

  int tid = threadIdx.x;
  int lane = tid & 63;
  int wave = tid >> 6;  // 0..7
  int wr = wave >> 1;   // 0..3: rows wr*32
  int wc = wave & 1;    // 0..1: cols wc*64
  int g = (blockIdx.z == 0) ? 3 : (int)blockIdx.z - 1;  // heavy g3 first
  // XCD-aware swizzle (R18-verified: FETCH 21->13.9 MB).
  int fid = (int)blockIdx.x + 32 * (int)blockIdx.y;  // 0..1023 in phase
  int swz = (fid & 7) * 128 + (fid >> 3);
  int bi = swz & 31;
  int bj = swz >> 5;
  int rowbase = bi * 128;
  int colbase = bj * 128;

  const ushort* Ab;
  const ushort* Bb;
  int nslab;
  float* rs;  // row-type slot base (slot = bj*2 + wc, 64 slots)
  float* cs;  // col-type slot base (slot = bi*4 + wr, 128 slots)
  int rslot = (bj * 2 + wc) * 4096;
  int cslot = (bi * 4 + wr) * 4096;
  if (g == 3) {
    Ab = nrm1;       Bb = nrm2;       nslab = 3;
    rs = parts + OFF_RS3 + rslot; cs = nullptr;
  } else if (g == 0) {
    Ab = nrm1;       Bb = nrm1 + 128; nslab = 1;
    rs = parts + OFF_RS0 + rslot; cs = parts + OFF_CS0 + cslot;
  } else if (g == 1) {
    Ab = nrm1;       Bb = nrm1 + 256; nslab = 1;
    rs = parts + OFF_RS1 + rslot; cs = parts + OFF_CS1 + cslot;
  } else {
    Ab = nrm1 + 128; Bb = nrm1 + 256; nslab = 1;
    rs = parts + OFF_RS2 + rslot; cs = parts + OFF_CS2 + cslot;
  }

  // Staging: each wave stages rows [wave*16, +16) of A and B per kslice.
  // Lane l -> row +(l>>2), chunk (l&3); source chunk pre-swizzled by
  // ((l>>3)&3) = ((row mod 16)>>1)&3 (R2-verified).
  int srow = lane >> 2;
  int schunk = ((lane & 3) ^ ((lane >> 3) & 3)) << 3;
  const ushort* gA =
      Ab + (size_t)(rowbase + wave * 16 + srow) * KCAT + schunk;
  const ushort* gB =
      Bb + (size_t)(colbase + wave * 16 + srow) * KCAT + schunk;

  // Fragment reads: row = grp*16 + rsel, logical chunk = lane>>4,
  // physical slot = chunk ^ ((rsel>>1)&3).
  int rsel = lane & 15;
  int slot8 = (((lane >> 4) ^ ((rsel >> 1) & 3)) << 3);

  f32x4 acc[2][4] = {};

  for (int slab = 0; slab < nslab; ++slab) {
    if (slab) {
      __builtin_amdgcn_s_barrier();       // prev slab reads done everywhere
      __builtin_amdgcn_sched_barrier(0);  // keep stage below the barrier
    }
    int k0 = slab * 128;
#pragma unroll
    for (int s = 0; s < 4; ++s) {
      gload16(gA + k0 + s * 32, &As[s][wave * 16][0]);
      gload16(gB + k0 + s * 32, &Bs[s][wave * 16][0]);
    }
    asm volatile("s_waitcnt vmcnt(0)" ::: "memory");
    __builtin_amdgcn_s_barrier();
    __builtin_amdgcn_sched_barrier(0);  // no LDS-read hoisting above barrier

    if (g == 3) {
#pragma unroll
      for (int kk = 0; kk < 4; ++kk) {
        short8 af[2], bf[4];
#pragma unroll
        for (int m = 0; m < 2; ++m)
          af[m] = *(const short8*)&As[kk][wr * 32 + m * 16 + rsel][slot8];
#pragma unroll
        for (int n = 0; n < 4; ++n)
          bf[n] = *(const short8*)&Bs[kk][wc * 64 + n * 16 + rsel][slot8];
#pragma unroll
        for (int m = 0; m < 2; ++m)
#pragma unroll
          for (int n = 0; n < 4; ++n)
            acc[m][n] = __builtin_amdgcn_mfma_f32_16x16x32_bf16(
                bf[n], af[m], acc[m][n], 0, 0, 0);
      }
    } else {
#pragma unroll
      for (int kk = 0; kk < 4; ++kk) {
        short8 af[2], bf[4];
#pragma unroll
        for (int m = 0; m < 2; ++m)
          af[m] = *(const short8*)&As[kk][wr * 32 + m * 16 + rsel][slot8];
#pragma unroll
        for (int n = 0; n < 4; ++n)
          bf[n] = *(const short8*)&Bs[kk][wc * 64 + n * 16 + rsel][slot8];
#pragma unroll
        for (int m = 0; m < 2; ++m)
#pragma unroll
          for (int n = 0; n < 4; ++n)
            acc[m][n] = __builtin_amdgcn_mfma_f32_16x16x32_bf16(
                af[m], bf[n], acc[m][n], 0, 0, 0);
      }
    }
  }

  if (g == 3)
    flush_cheap8(acc, rs, rowbase + wr * 32, lane);
  else
    flush_full8(acc, rs, cs, rowbase + wr * 32, colbase + wc * 64, lane);
}

// ---------------------------------------------------------------------------
// Stage 1: fold partial slots. FIX vs R20: compile-time trip counts per
// branch (runtime `cnt` loop defeated unroll/pipelining -> 112 blocks of
// serialized 600-cy strided loads ~= +35 us). Each side is a constant-bound
// unroll-8 loop (R17's proven codegen).
__global__ __launch_bounds__(256) void reduce_parts_kernel(
    const float* __restrict__ parts, float* __restrict__ sums7) {
  int f = blockIdx.x * 256 + threadIdx.x;  // 0 .. 7*4096-1
  int a = f >> 12;                         // 0..6
  int i = f & 4095;
  float s = 0.0f;
  if (a < 4) {
    const float* p = parts + (size_t)(a * 64) * 4096 + i;
#pragma unroll 8
    for (int slot = 0; slot < 64; ++slot) s += p[(size_t)slot * 4096];
  } else {
    const float* p = parts + (size_t)(256 + (a - 4) * 128) * 4096 + i;
#pragma unroll 8
    for (int slot = 0; slot < 128; ++slot) s += p[(size_t)slot * 4096];
  }
  sums7[f] = s;  // order: rs0, rs1, rs2, rs3, cs0, cs1, cs2
}

// ---------------------------------------------------------------------------
// Stage 2: final loss from folded sums (163 KB). Single block, plain store.
__global__ __launch_bounds__(256) void loss_kernel(
    const float* __restrict__ s7, const float* __restrict__ dxyz,
    float* __restrict__ out) {
  int tid = threadIdx.x;
  float acc = 0.0f;
  for (int i = tid; i < BHALF; i += 256) {
    float rs0 = s7[i];
    float rs1 = s7[4096 + i];
    float rs2 = s7[2 * 4096 + i];
    float rs3 = s7[3 * 4096 + i];
    float cs0 = s7[4 * 4096 + i];
    float cs1 = s7[5 * 4096 + i];
    float cs2 = s7[6 * 4096 + i];
    float dxv = dxyz[i];
    float dyv = dxyz[4096 + i];
    float dzv = dxyz[2 * 4096 + i];
    float lx = logf(rs0 + rs1) - TEMP_INV * dxv;
    float ly = logf(cs0 + rs2) - TEMP_INV * dyv;
    float lz = logf(cs1 + cs2) - TEMP_INV * dzv;
    float lv = logf(rs3) - TEMP_INV * (dxv + dyv + dzv);
    acc += lx + ly + lz + lv;
  }
  __shared__ float red[4];
#pragma unroll
  for (int m = 1; m < 64; m <<= 1) acc += __shfl_xor(acc, m, 64);
  if ((tid & 63) == 0) red[tid >> 6] = acc;
  __syncthreads();
  if (tid == 0)
    out[0] = (red[0] + red[1] + red[2] + red[3]) * (1.0f / 4096.0f);
}

// ---------------------------------------------------------------------------
extern "C" void kernel_launch(void* const* d_in, const int* in_sizes, int n_in,
                              void* d_out, int out_size, void* d_ws,
                              size_t ws_size, hipStream_t stream) {
  const float* x = (const float*)d_in[0];
  const float* y = (const float*)d_in[1];
  const float* z = (const float*)d_in[2];
  char* ws = (char*)d_ws;
  ushort* nrm1 = (ushort*)ws;                       // 4096*384 bf16
  ushort* nrm2 = nrm1 + (size_t)BHALF * KCAT;       // 4096*384 bf16
  float* parts = (float*)(ws + 2 * (size_t)BHALF * KCAT * sizeof(ushort));
  float* dxyz = parts + PARTS_TOTAL;                // 3*4096 fp32
  float* sums7 = dxyz + 3 * 4096;                   // 7*4096 fp32

  norm_diag_kernel<<<3 * BHALF / 4, 256, 0, stream>>>(x, y, z, nrm1, nrm2,
                                                      dxyz);
  gram_slab_kernel<<<dim3(32, 32, 4), 512, 0, stream>>>(nrm1, nrm2, parts);
  reduce_parts_kernel<<<112, 256, 0, stream>>>(parts, sums7);
  loss_kernel<<<1, 256, 0, stream>>>(sums7, dxyz, (float*)d_out);
}